// Round 16
// baseline (161.481 us; speedup 1.0000x reference)
//
#include <hip/hip_runtime.h>

typedef __bf16 bf16x8 __attribute__((ext_vector_type(8)));
typedef short  s16x8  __attribute__((ext_vector_type(8)));
typedef float  f32x4  __attribute__((ext_vector_type(4)));

#define DEVINL __device__ __forceinline__

DEVINL unsigned short f2bf(float f) {
  unsigned int u = __builtin_bit_cast(unsigned int, f);
  u += 0x7fffu + ((u >> 16) & 1u);   // round-to-nearest-even
  return (unsigned short)(u >> 16);
}

DEVINL void async16(const void* g, void* l) {
  __builtin_amdgcn_global_load_lds(
      (const __attribute__((address_space(1))) unsigned int*)g,
      (__attribute__((address_space(3))) unsigned int*)l, 16, 0, 0);
}

// ---------------- fused prep kernel ----------------

__global__ __launch_bounds__(256) void prep(
    const float* __restrict__ x, const float* __restrict__ W1,
    const float* __restrict__ W2, const float* __restrict__ theta,
    const float* __restrict__ wre, const float* __restrict__ wim,
    unsigned short* __restrict__ xb, unsigned short* __restrict__ w1t,
    unsigned short* __restrict__ w2t, float* __restrict__ c1) {
  __shared__ unsigned short tile[32][33];
  const int b = blockIdx.x;
  const int tid = threadIdx.x;
  if (b < 1024) {
    int i = b * 256 + tid;
#pragma unroll
    for (int k = 0; k < 8; ++k, i += 262144) {
      float4 v = ((const float4*)x)[i];
      ushort4 o;
      o.x = f2bf(v.x); o.y = f2bf(v.y); o.z = f2bf(v.z); o.w = f2bf(v.w);
      ((ushort4*)xb)[i] = o;
    }
  } else if (b < 5120) {
    int bb = b - 1024;                      // W1: R=1024, C=4096
    int bc = (bb & 127) * 32, br = (bb >> 7) * 32;
    int tx = tid & 31, ty = tid >> 5;
#pragma unroll
    for (int i = 0; i < 32; i += 8)
      tile[ty + i][tx] = f2bf(W1[(size_t)(br + ty + i) * 4096 + (bc + tx)]);
    __syncthreads();
#pragma unroll
    for (int i = 0; i < 32; i += 8)
      w1t[(size_t)(bc + ty + i) * 1024 + (br + tx)] = tile[tx][ty + i];
  } else if (b < 9216) {
    int bb = b - 5120;                      // W2: R=4096, C=1024
    int bc = (bb & 31) * 32, br = (bb >> 5) * 32;
    int tx = tid & 31, ty = tid >> 5;
#pragma unroll
    for (int i = 0; i < 32; i += 8)
      tile[ty + i][tx] = f2bf(W2[(size_t)(br + ty + i) * 1024 + (bc + tx)]);
    __syncthreads();
#pragma unroll
    for (int i = 0; i < 32; i += 8)
      w2t[(size_t)(bc + ty + i) * 4096 + (br + tx)] = tile[tx][ty + i];
  } else {
    int i = (b - 9216) * 256 + tid;         // qconst, n = 4096
    float t = theta[i];
    c1[i] = (cosf(t) * wre[i] + sinf(t) * wim[i]) * wim[i] * 0.1f;
  }
}

// ================= GEMM1: actb = relu(qt(xb @ w1t^T + b1)) =================
// R16: 128x256 tile, BK=64, NT=16, 1024 blocks, 3-buffer LDS ring with
// 2-tile-ahead staging (deep async pipeline, never drains mid-loop).
// K-loop geometry (aRd/bRd/stage macros) byte-identical to the proven
// gemm2k kernel (0 conflicts, VGPR 88).
// Ring ledger: window T reads buf T%3; stages tile T+2 -> buf (T+2)%3
//  (= tile T-1's buffer: its reads drained by window T-1's lgkm0s before
//  that window's barriers; stage issues after them -> WAR-safe).
// vmcnt: window T stages 6 loads (A 2 + B 4). End-of-window vmcnt(6)
//  leaves exactly tile T+2's 6 loads in flight and certifies everything
//  older -> tile T+1 (staged in window T-1) is ready for window T+1.
//  Tail: T==NT-2 stages nothing -> vmcnt(0) drains tile NT-1; last window
//  no wait. Prologue: stage tile0->buf0 (6), tile1->buf1 (6); vmcnt(6)
//  certifies tile0 (tile1 stays in flight).
// Epilogue scratch = buf0's A region (16K): tile15 lives in buf0, its
//  reads are lgkm0-drained before window15's final barrier -> free.

__global__ __launch_bounds__(512, 1) void gemm1k(
    const unsigned short* __restrict__ A,    // xb  [8192][1024]
    const unsigned short* __restrict__ Bt,   // w1t [4096][1024]
    const float* __restrict__ bias,
    const float* __restrict__ theta,
    const float* __restrict__ c1,
    unsigned short* __restrict__ Cout) {     // actb [8192][4096]
  constexpr int K = 1024, N = 4096, NT = 16;
  constexpr int ABYTES = 16384, AH = 8192;
  constexpr int BUFSZ = 49152;               // A 16K + B 32K
  constexpr int nTilesN = 16;

  __shared__ __align__(16) char lds[3 * BUFSZ];   // 144K total

  int nwg = gridDim.x;                        // 1024, %8==0
  int wg = blockIdx.x;
  int sw = (wg & 7) * (nwg >> 3) + (wg >> 3);
  int rowBase = (sw / nTilesN) * 128;
  int colBase = (sw % nTilesN) * 256;

  const int t = threadIdx.x;
  const int lane = t & 63;
  const int wid = t >> 6;
  const int wr = wid >> 2, wc = wid & 3;      // 2M x 4N waves, 64x64/wave
  const int lr = lane & 15;
  const int lg = lane >> 4;
  const int r7 = lane & 7;

  const int srow = t >> 3;                    // 0..63
  const int scolB = ((t & 7) * 16) ^ ((srow & 7) << 4);
  const unsigned short* aSrcB = A  + (size_t)(rowBase + srow) * K + (scolB >> 1);
  const unsigned short* bSrcB = Bt + (size_t)(colBase + srow) * K + (scolB >> 1);

  const int aRd = (wr * 64 + lr) * 128 + ((lg ^ r7) << 4);
  const int bRd = ABYTES + (wc * 64 + lr) * 128 + ((lg ^ r7) << 4);

  f32x4 acc[4][4] = {};
  bf16x8 a[2][2], b[4][2];

#define STAGE_A(S, P) do {                                                  \
    async16(aSrcB + (size_t)(S) * 64, &lds[(P) * BUFSZ + t * 16]);          \
    async16(aSrcB + ((size_t)64 * K + (size_t)(S) * 64),                    \
            &lds[(P) * BUFSZ + AH + t * 16]);                               \
  } while (0)
#define STAGE_B(S, P) do {                                                  \
    _Pragma("unroll") for (int u = 0; u < 4; ++u)                           \
      async16(bSrcB + ((size_t)(u * 64) * K + (size_t)(S) * 64),            \
              &lds[(P) * BUFSZ + ABYTES + u * 8192 + t * 16]);              \
  } while (0)
#define LOAD_A(MHh, P)                                                      \
  _Pragma("unroll") for (int mi = 0; mi < 2; ++mi)                          \
  _Pragma("unroll") for (int ks = 0; ks < 2; ++ks)                          \
    a[mi][ks] = __builtin_bit_cast(bf16x8, *(const s16x8*)&lds[             \
        (P) * BUFSZ + ((aRd + ((MHh) * 2 + mi) * 2048) ^ (ks << 6))])
#define LOAD_B(NHh, P)                                                      \
  _Pragma("unroll") for (int nn = 0; nn < 2; ++nn)                          \
  _Pragma("unroll") for (int ks = 0; ks < 2; ++ks)                          \
    b[(NHh) * 2 + nn][ks] = __builtin_bit_cast(bf16x8, *(const s16x8*)&lds[ \
        (P) * BUFSZ + ((bRd + ((NHh) * 2 + nn) * 2048) ^ (ks << 6))])
#define QUAD(MHh, NHh)                                                      \
  __builtin_amdgcn_s_setprio(1);                                            \
  _Pragma("unroll") for (int mi = 0; mi < 2; ++mi)                          \
  _Pragma("unroll") for (int nn = 0; nn < 2; ++nn)                          \
  _Pragma("unroll") for (int ks = 0; ks < 2; ++ks)                          \
    acc[(MHh) * 2 + mi][(NHh) * 2 + nn] =                                   \
        __builtin_amdgcn_mfma_f32_16x16x32_bf16(                            \
            a[mi][ks], b[(NHh) * 2 + nn][ks],                               \
            acc[(MHh) * 2 + mi][(NHh) * 2 + nn], 0, 0, 0);                  \
  __builtin_amdgcn_s_setprio(0)
#define BAR() __builtin_amdgcn_s_barrier()
#define LG0() asm volatile("s_waitcnt lgkmcnt(0)" ::: "memory")
#define WIN(T, P, PN) do {                                                  \
    /* half 1 */                                                            \
    LOAD_A(0, P); LOAD_B(0, P);                                             \
    if ((T) + 2 < NT) STAGE_A((T) + 2, PN);                                 \
    QUAD(0, 0);                                                             \
    LOAD_B(1, P);                                                           \
    QUAD(0, 1);                                                             \
    LG0(); BAR();                                                           \
    /* half 2 */                                                            \
    LOAD_A(1, P);                                                           \
    if ((T) + 2 < NT) STAGE_B((T) + 2, PN);                                 \
    QUAD(1, 0);                                                             \
    QUAD(1, 1);                                                             \
    LG0();                                                                  \
    if ((T) + 2 < NT) {                                                     \
      asm volatile("s_waitcnt vmcnt(6)" ::: "memory");                      \
    } else if ((T) + 1 < NT) {                                              \
      asm volatile("s_waitcnt vmcnt(0)" ::: "memory");                      \
    }                                                                       \
    BAR();                                                                  \
  } while (0)

  // prologue: tile0 -> buf0, tile1 -> buf1; certify tile0 (tile1 in flight)
  STAGE_A(0, 0); STAGE_B(0, 0);
  STAGE_A(1, 1); STAGE_B(1, 1);
  asm volatile("s_waitcnt vmcnt(6)" ::: "memory");
  BAR();

  // NT=16: windows 0..14 in 5 ring rounds, then window 15 (15%3==0)
  for (int T = 0; T < NT - 1; T += 3) {
    WIN(T, 0, 2);
    WIN(T + 1, 1, 0);
    WIN(T + 2, 2, 1);
  }
  WIN(NT - 1, 0, 2);

#undef WIN
#undef QUAD
#undef LOAD_A
#undef LOAD_B
#undef STAGE_A
#undef STAGE_B
#undef BAR
#undef LG0

  // ---- fused epilogue (bias + quantum + relu), full-line bf16 stores ----
  // scratch = buf0 A region (per-wave 2KB)
  const int ocol0 = colBase + wc * 64 + lr;
  float bvv[4], thv[4], ccv[4];
#pragma unroll
  for (int ni = 0; ni < 4; ++ni) {
    int n = ocol0 + ni * 16;
    bvv[ni] = bias[n]; thv[ni] = theta[n]; ccv[ni] = c1[n];
  }
  const int SB = wid * 2048;
  const size_t growB = (size_t)(rowBase + wr * 64) * N;
  const int rd = lane >> 3;                // 0..7
  const int bo = (lane & 7) * 16;          // 0..112
#pragma unroll
  for (int mi = 0; mi < 4; ++mi) {
#pragma unroll
    for (int ni = 0; ni < 4; ++ni) {
#pragma unroll
      for (int r = 0; r < 4; ++r) {
        int row16 = lg * 4 + r;
        float h = acc[mi][ni][r] + bvv[ni];
        float q = h + ccv[ni] * __sinf(thv[ni] + 0.1f * h);
        unsigned short v = f2bf(fmaxf(q, 0.f));
        int ad = SB + row16 * 128 +
                 (((ni * 16 + lr) * 2) ^ ((row16 & 7) << 4));
        *(unsigned short*)&lds[ad] = v;
      }
    }
    s16x8 w0 = *(const s16x8*)&lds[SB + rd * 128 + (bo ^ ((rd & 7) << 4))];
    s16x8 w1 = *(const s16x8*)&lds[SB + (rd + 8) * 128 +
                                   (bo ^ ((rd & 7) << 4))];
    unsigned short* dst = Cout + growB + (size_t)(mi * 16 + rd) * N +
                          colBase + wc * 64 + (lane & 7) * 8;
    *(s16x8*)dst = w0;
    *(s16x8*)(dst + (size_t)8 * N) = w1;   // rows rd and rd+8
  }
}

// ================= GEMM2: out = actb @ w2t^T + b2 (fp32) =================
// R15 verbatim (2-barrier window schedule; improved 73 -> ~60).

__global__ __launch_bounds__(512, 1) void gemm2k(
    const unsigned short* __restrict__ A,    // actb [8192][4096]
    const unsigned short* __restrict__ Bt,   // w2t  [1024][4096]
    const float* __restrict__ bias,
    float* __restrict__ Cout) {              // out [8192][1024]
  constexpr int K = 4096, N = 1024, NT = 64;
  constexpr int WROWS = 64, M_REP = 4, MH = 2;
  constexpr int ABYTES = 16384, AH = 8192, AL = 1;
  constexpr int BUFSZ = 49152;
  constexpr int nTilesN = 4;

  __shared__ __align__(16) char lds[2 * BUFSZ + 32768];

  int nwg = gridDim.x;
  int wg = blockIdx.x;
  int sw = (wg & 7) * (nwg >> 3) + (wg >> 3);
  int rowBase = (sw / nTilesN) * 128;
  int colBase = (sw % nTilesN) * 256;

  const int t = threadIdx.x;
  const int lane = t & 63;
  const int wid = t >> 6;
  const int wr = wid >> 2, wc = wid & 3;
  const int lr = lane & 15;
  const int lg = lane >> 4;
  const int r7 = lane & 7;

  const int srow = t >> 3;
  const int scolB = ((t & 7) * 16) ^ ((srow & 7) << 4);
  const unsigned short* aSrcB = A  + (size_t)(rowBase + srow) * K + (scolB >> 1);
  const unsigned short* bSrcB = Bt + (size_t)(colBase + srow) * K + (scolB >> 1);

  const int aRd = (wr * WROWS + lr) * 128 + ((lg ^ r7) << 4);
  const int bRd = ABYTES + (wc * 64 + lr) * 128 + ((lg ^ r7) << 4);

  f32x4 acc[M_REP][4] = {};
  bf16x8 a[MH][2], b[4][2];

#define STAGE_AU(S, U, P)                                                   \
  async16(aSrcB + ((size_t)((U) * 64) * K + (size_t)(S) * 64),              \
          &lds[(P) * BUFSZ + (U) * AH + t * 16])
#define STAGE_BU(S, U, P) do {                                              \
    _Pragma("unroll") for (int j = 0; j < 2; ++j)                           \
      async16(bSrcB + ((size_t)((U) * 128 + j * 64) * K + (size_t)(S) * 64),\
              &lds[(P) * BUFSZ + ABYTES + (U) * 16384 + j * 8192 + t * 16]);\
  } while (0)
#define LOAD_A(MHh, P)                                                      \
  _Pragma("unroll") for (int mi = 0; mi < MH; ++mi)                         \
  _Pragma("unroll") for (int ks = 0; ks < 2; ++ks)                          \
    a[mi][ks] = __builtin_bit_cast(bf16x8, *(const s16x8*)&lds[             \
        (P) * BUFSZ + ((aRd + ((MHh) * MH + mi) * 2048) ^ (ks << 6))])
#define LOAD_B(NHh, P)                                                      \
  _Pragma("unroll") for (int nn = 0; nn < 2; ++nn)                          \
  _Pragma("unroll") for (int ks = 0; ks < 2; ++ks)                          \
    b[(NHh) * 2 + nn][ks] = __builtin_bit_cast(bf16x8, *(const s16x8*)&lds[ \
        (P) * BUFSZ + ((bRd + ((NHh) * 2 + nn) * 2048) ^ (ks << 6))])
#define QUAD(MHh, NHh)                                                      \
  __builtin_amdgcn_s_setprio(1);                                            \
  _Pragma("unroll") for (int mi = 0; mi < MH; ++mi)                         \
  _Pragma("unroll") for (int nn = 0; nn < 2; ++nn)                          \
  _Pragma("unroll") for (int ks = 0; ks < 2; ++ks)                          \
    acc[(MHh) * MH + mi][(NHh) * 2 + nn] =                                  \
        __builtin_amdgcn_mfma_f32_16x16x32_bf16(                            \
            a[mi][ks], b[(NHh) * 2 + nn][ks],                               \
            acc[(MHh) * MH + mi][(NHh) * 2 + nn], 0, 0, 0);                 \
  __builtin_amdgcn_s_setprio(0)
#define BAR() __builtin_amdgcn_s_barrier()
#define LG0() asm volatile("s_waitcnt lgkmcnt(0)" ::: "memory")
#define WIN(T, P) do {                                                      \
    /* half 1 */                                                            \
    LOAD_A(0, P); LOAD_B(0, P);                                             \
    if ((T) + 1 < NT) {                                                     \
      STAGE_AU((T) + 1, 0, (P) ^ 1);                                        \
      STAGE_AU((T) + 1, 1, (P) ^ 1);                                        \
    }                                                                       \
    QUAD(0, 0);                                                             \
    LOAD_B(1, P);                                                           \
    QUAD(0, 1);                                                             \
    LG0(); BAR();                                                           \
    /* half 2 */                                                            \
    LOAD_A(1, P);                                                           \
    if ((T) + 2 < NT) {                                                     \
      STAGE_BU((T) + 2, 0, P);                                              \
      STAGE_BU((T) + 2, 1, P);                                              \
    }                                                                       \
    QUAD(1, 0);                                                             \
    QUAD(1, 1);                                                             \
    LG0();                                                                  \
    if ((T) < NT - 2) {                                                     \
      asm volatile("s_waitcnt vmcnt(4)" ::: "memory");                      \
    } else if ((T) == NT - 2) {                                             \
      asm volatile("s_waitcnt vmcnt(0)" ::: "memory");                      \
    }                                                                       \
    BAR();                                                                  \
  } while (0)

  STAGE_AU(0, 0, 0); STAGE_AU(0, 1, 0);
  STAGE_BU(0, 0, 0); STAGE_BU(0, 1, 0);
  STAGE_BU(1, 0, 1); STAGE_BU(1, 1, 1);
  asm volatile("s_waitcnt vmcnt(4)" ::: "memory");
  BAR();

  for (int T = 0; T < NT; T += 2) {
    WIN(T, 0);
    WIN(T + 1, 1);
  }
#undef WIN
#undef QUAD
#undef LOAD_A
#undef LOAD_B
#undef STAGE_AU
#undef STAGE_BU
#undef BAR

  // ---- full-line fp32 epilogue via per-wave 4KB scratch ----
  const int ocol0 = colBase + wc * 64 + lr;
  float bvv[4];
#pragma unroll
  for (int ni = 0; ni < 4; ++ni) bvv[ni] = bias[ocol0 + ni * 16];
  const int SB = 2 * BUFSZ + wid * 4096;
  const int orowB = rowBase + wr * WROWS;
  const int rd = lane >> 3;                  // 0..7
  const int bo = (lane & 7) * 16;            // 0..112
#pragma unroll
  for (int mi = 0; mi < M_REP; ++mi) {
#pragma unroll
    for (int ni = 0; ni < 4; ++ni) {
#pragma unroll
      for (int r = 0; r < 4; ++r) {
        int row16 = lg * 4 + r;
        int ad = SB + row16 * 256 +
                 (((ni * 16 + lr) * 4) ^ ((row16 & 7) << 4));
        *(float*)&lds[ad] = acc[mi][ni][r] + bvv[ni];
      }
    }
    asm volatile("s_waitcnt lgkmcnt(0)" ::: "memory");
    f32x4 v00 = *(const f32x4*)&lds[SB + rd * 256 + (bo ^ ((rd & 7) << 4))];
    f32x4 v01 = *(const f32x4*)&lds[SB + rd * 256 +
                                    ((bo + 128) ^ ((rd & 7) << 4))];
    f32x4 v10 = *(const f32x4*)&lds[SB + (rd + 8) * 256 +
                                    (bo ^ ((rd & 7) << 4))];
    f32x4 v11 = *(const f32x4*)&lds[SB + (rd + 8) * 256 +
                                    ((bo + 128) ^ ((rd & 7) << 4))];
    float* dst0 = Cout + (size_t)(orowB + mi * 16 + rd) * N +
                  colBase + wc * 64 + (lane & 7) * 4;
    *(f32x4*)dst0 = v00;
    *(f32x4*)(dst0 + 32) = v01;
    float* dst1 = dst0 + (size_t)8 * N;
    *(f32x4*)dst1 = v10;
    *(f32x4*)(dst1 + 32) = v11;
    asm volatile("s_waitcnt lgkmcnt(0)" ::: "memory");
  }
#undef LG0
}

// ---------------- launch ----------------

extern "C" void kernel_launch(void* const* d_in, const int* in_sizes, int n_in,
                              void* d_out, int out_size, void* d_ws,
                              size_t ws_size, hipStream_t stream) {
  const float* x     = (const float*)d_in[0];
  const float* W1    = (const float*)d_in[1];
  const float* b1    = (const float*)d_in[2];
  const float* theta = (const float*)d_in[3];
  const float* qwr   = (const float*)d_in[4];
  const float* qwi   = (const float*)d_in[5];
  const float* W2    = (const float*)d_in[6];
  const float* b2    = (const float*)d_in[7];
  float* out = (float*)d_out;

  const int DF = 4096;
  size_t need = ((size_t)96 << 20) + DF * sizeof(float);
  if (ws_size < need) return;

  char* ws = (char*)d_ws;
  unsigned short* xb   = (unsigned short*)ws;                          // 16 MiB
  unsigned short* w1t  = (unsigned short*)(ws + ((size_t)16 << 20));   //  8 MiB
  unsigned short* w2t  = (unsigned short*)(ws + ((size_t)24 << 20));   //  8 MiB
  unsigned short* actb = (unsigned short*)(ws + ((size_t)32 << 20));   // 64 MiB
  float* c1 = (float*)(ws + ((size_t)96 << 20));

  prep<<<9232, 256, 0, stream>>>(x, W1, W2, theta, qwr, qwi,
                                 xb, w1t, w2t, c1);
  gemm1k<<<1024, 512, 0, stream>>>(xb, w1t, b1, theta, c1, actb);
  gemm2k<<<256, 512, 0, stream>>>(actb, w2t, b2, out);
}

// Round 17
// 146.277 us; speedup vs baseline: 1.1039x; 1.1039x over previous
//
#include <hip/hip_runtime.h>

typedef __bf16 bf16x8 __attribute__((ext_vector_type(8)));
typedef short  s16x8  __attribute__((ext_vector_type(8)));
typedef float  f32x4  __attribute__((ext_vector_type(4)));

#define DEVINL __device__ __forceinline__

DEVINL unsigned short f2bf(float f) {
  unsigned int u = __builtin_bit_cast(unsigned int, f);
  u += 0x7fffu + ((u >> 16) & 1u);   // round-to-nearest-even
  return (unsigned short)(u >> 16);
}

DEVINL void async16(const void* g, void* l) {
  __builtin_amdgcn_global_load_lds(
      (const __attribute__((address_space(1))) unsigned int*)g,
      (__attribute__((address_space(3))) unsigned int*)l, 16, 0, 0);
}

// ---------------- fused prep kernel ----------------

__global__ __launch_bounds__(256) void prep(
    const float* __restrict__ x, const float* __restrict__ W1,
    const float* __restrict__ W2, const float* __restrict__ theta,
    const float* __restrict__ wre, const float* __restrict__ wim,
    unsigned short* __restrict__ xb, unsigned short* __restrict__ w1t,
    unsigned short* __restrict__ w2t, float* __restrict__ c1) {
  __shared__ unsigned short tile[32][33];
  const int b = blockIdx.x;
  const int tid = threadIdx.x;
  if (b < 1024) {
    int i = b * 256 + tid;
#pragma unroll
    for (int k = 0; k < 8; ++k, i += 262144) {
      float4 v = ((const float4*)x)[i];
      ushort4 o;
      o.x = f2bf(v.x); o.y = f2bf(v.y); o.z = f2bf(v.z); o.w = f2bf(v.w);
      ((ushort4*)xb)[i] = o;
    }
  } else if (b < 5120) {
    int bb = b - 1024;                      // W1: R=1024, C=4096
    int bc = (bb & 127) * 32, br = (bb >> 7) * 32;
    int tx = tid & 31, ty = tid >> 5;
#pragma unroll
    for (int i = 0; i < 32; i += 8)
      tile[ty + i][tx] = f2bf(W1[(size_t)(br + ty + i) * 4096 + (bc + tx)]);
    __syncthreads();
#pragma unroll
    for (int i = 0; i < 32; i += 8)
      w1t[(size_t)(bc + ty + i) * 1024 + (br + tx)] = tile[tx][ty + i];
  } else if (b < 9216) {
    int bb = b - 5120;                      // W2: R=4096, C=1024
    int bc = (bb & 31) * 32, br = (bb >> 5) * 32;
    int tx = tid & 31, ty = tid >> 5;
#pragma unroll
    for (int i = 0; i < 32; i += 8)
      tile[ty + i][tx] = f2bf(W2[(size_t)(br + ty + i) * 1024 + (bc + tx)]);
    __syncthreads();
#pragma unroll
    for (int i = 0; i < 32; i += 8)
      w2t[(size_t)(bc + ty + i) * 4096 + (br + tx)] = tile[tx][ty + i];
  } else {
    int i = (b - 9216) * 256 + tid;         // qconst, n = 4096
    float t = theta[i];
    c1[i] = (cosf(t) * wre[i] + sinf(t) * wim[i]) * wim[i] * 0.1f;
  }
}

// ================= GEMM1: actb = relu(qt(xb @ w1t^T + b1)) =================
// R15 verbatim (best measured: 72.7 us, 945 TF, 0 conflicts, no spill).
// 256x256 tile, BK=64, NT=16, REPS=2, 2-barrier window schedule.

__global__ __launch_bounds__(512, 1) void gemm1k(
    const unsigned short* __restrict__ A,    // xb  [8192][1024]
    const unsigned short* __restrict__ Bt,   // w1t [4096][1024]
    const float* __restrict__ bias,
    const float* __restrict__ theta,
    const float* __restrict__ c1,
    unsigned short* __restrict__ Cout) {     // actb [8192][4096]
  constexpr int K = 1024, N = 4096, NT = 16, REPS = 2;
  constexpr int WROWS = 128, M_REP = 8, MH = 4;
  constexpr int ABYTES = 32768, AH = 16384, AL = 2;
  constexpr int BUFSZ = 65536;
  constexpr int nTilesN = 8;                 // 4096 / 512

  __shared__ __align__(16) char lds[2 * BUFSZ + 16384];

  int nwg = gridDim.x;
  int wg = blockIdx.x;
  int sw = (wg & 7) * (nwg >> 3) + (wg >> 3);
  int rowBase = (sw / nTilesN) * 256;
  int colBase = (sw % nTilesN) * 512;

  const int t = threadIdx.x;
  const int lane = t & 63;
  const int wid = t >> 6;
  const int wr = wid >> 2, wc = wid & 3;
  const int lr = lane & 15;
  const int lg = lane >> 4;
  const int r7 = lane & 7;

  const int srow = t >> 3;
  const int scolB = ((t & 7) * 16) ^ ((srow & 7) << 4);
  const unsigned short* aSrcB = A  + (size_t)(rowBase + srow) * K + (scolB >> 1);
  const unsigned short* bSrcB = Bt + (size_t)(colBase + srow) * K + (scolB >> 1);

  const int aRd = (wr * WROWS + lr) * 128 + ((lg ^ r7) << 4);
  const int bRd = ABYTES + (wc * 64 + lr) * 128 + ((lg ^ r7) << 4);

#define STAGE_AU(S, U, P) do {                                              \
    _Pragma("unroll") for (int j = 0; j < AL; ++j)                          \
      async16(aSrcB + ((size_t)((U) * WROWS + j * 64) * K + (size_t)(S) * 64),\
              &lds[(P) * BUFSZ + (U) * AH + j * 8192 + t * 16]);            \
  } while (0)
#define STAGE_BU(SRC, S, U, P) do {                                         \
    _Pragma("unroll") for (int j = 0; j < 2; ++j)                           \
      async16((SRC) + ((size_t)((U) * 128 + j * 64) * K + (size_t)(S) * 64),\
              &lds[(P) * BUFSZ + ABYTES + (U) * 16384 + j * 8192 + t * 16]);\
  } while (0)
#define LOAD_A(MHh, P)                                                      \
  _Pragma("unroll") for (int mi = 0; mi < MH; ++mi)                         \
  _Pragma("unroll") for (int ks = 0; ks < 2; ++ks)                          \
    a[mi][ks] = __builtin_bit_cast(bf16x8, *(const s16x8*)&lds[             \
        (P) * BUFSZ + ((aRd + ((MHh) * MH + mi) * 2048) ^ (ks << 6))])
#define LOAD_B(NHh, P)                                                      \
  _Pragma("unroll") for (int nn = 0; nn < 2; ++nn)                          \
  _Pragma("unroll") for (int ks = 0; ks < 2; ++ks)                          \
    b[(NHh) * 2 + nn][ks] = __builtin_bit_cast(bf16x8, *(const s16x8*)&lds[ \
        (P) * BUFSZ + ((bRd + ((NHh) * 2 + nn) * 2048) ^ (ks << 6))])
#define QUAD(MHh, NHh)                                                      \
  __builtin_amdgcn_s_setprio(1);                                            \
  _Pragma("unroll") for (int mi = 0; mi < MH; ++mi)                         \
  _Pragma("unroll") for (int nn = 0; nn < 2; ++nn)                          \
  _Pragma("unroll") for (int ks = 0; ks < 2; ++ks)                          \
    acc[(MHh) * MH + mi][(NHh) * 2 + nn] =                                  \
        __builtin_amdgcn_mfma_f32_16x16x32_bf16(                            \
            a[mi][ks], b[(NHh) * 2 + nn][ks],                               \
            acc[(MHh) * MH + mi][(NHh) * 2 + nn], 0, 0, 0);                 \
  __builtin_amdgcn_s_setprio(0)
#define BAR() __builtin_amdgcn_s_barrier()
#define LG0() asm volatile("s_waitcnt lgkmcnt(0)" ::: "memory")
#define WIN(T, P) do {                                                      \
    /* half 1 */                                                            \
    LOAD_A(0, P); LOAD_B(0, P);                                             \
    if ((T) + 1 < NT) {                                                     \
      STAGE_AU((T) + 1, 0, (P) ^ 1);                                        \
      STAGE_AU((T) + 1, 1, (P) ^ 1);                                        \
    }                                                                       \
    QUAD(0, 0);                                                             \
    LOAD_B(1, P);                                                           \
    QUAD(0, 1);                                                             \
    LG0(); BAR();                                                           \
    /* half 2 */                                                            \
    LOAD_A(1, P);                                                           \
    if ((T) + 2 < NT) {                                                     \
      STAGE_BU(bSrcR, (T) + 2, 0, P);                                       \
      STAGE_BU(bSrcR, (T) + 2, 1, P);                                       \
    }                                                                       \
    QUAD(1, 0);                                                             \
    QUAD(1, 1);                                                             \
    LG0();                                                                  \
    if ((T) < NT - 2) {                                                     \
      asm volatile("s_waitcnt vmcnt(4)" ::: "memory");                      \
    } else if ((T) == NT - 2) {                                             \
      asm volatile("s_waitcnt vmcnt(0)" ::: "memory");                      \
    }                                                                       \
    BAR();                                                                  \
  } while (0)

  STAGE_AU(0, 0, 0); STAGE_AU(0, 1, 0);
  STAGE_BU(bSrcB, 0, 0, 0); STAGE_BU(bSrcB, 0, 1, 0);
  STAGE_BU(bSrcB, 1, 0, 1); STAGE_BU(bSrcB, 1, 1, 1);
  asm volatile("s_waitcnt vmcnt(4)" ::: "memory");
  BAR();

  for (int rep = 0; rep < REPS; ++rep) {
    const unsigned short* bSrcR = bSrcB + (size_t)rep * 256 * K;
    f32x4 acc[M_REP][4] = {};
    bf16x8 a[MH][2], b[4][2];

    for (int T = 0; T < NT; T += 2) {
      WIN(T, 0);
      WIN(T + 1, 1);
    }

    if (rep + 1 < REPS) {
      const unsigned short* bSrcN = bSrcB + (size_t)(rep + 1) * 256 * K;
      STAGE_AU(0, 0, 0); STAGE_AU(0, 1, 0);
      STAGE_BU(bSrcN, 0, 0, 0); STAGE_BU(bSrcN, 0, 1, 0);
      STAGE_BU(bSrcN, 1, 0, 1); STAGE_BU(bSrcN, 1, 1, 1);
    }

    // ---- fused epilogue (bias + quantum + relu), full-line bf16 stores ----
    const int colR = colBase + rep * 256;
    const int ocol0 = colR + wc * 64 + lr;
    float bvv[4], thv[4], ccv[4];
#pragma unroll
    for (int ni = 0; ni < 4; ++ni) {
      int n = ocol0 + ni * 16;
      bvv[ni] = bias[n]; thv[ni] = theta[n]; ccv[ni] = c1[n];
    }
    const int SB = 2 * BUFSZ + wid * 2048;
    const size_t growB = (size_t)(rowBase + wr * WROWS) * N;
    const int rd = lane >> 3;                // 0..7
    const int bo = (lane & 7) * 16;          // 0..112
#pragma unroll
    for (int mi = 0; mi < M_REP; ++mi) {
#pragma unroll
      for (int ni = 0; ni < 4; ++ni) {
#pragma unroll
        for (int r = 0; r < 4; ++r) {
          int row16 = lg * 4 + r;
          float h = acc[mi][ni][r] + bvv[ni];
          float q = h + ccv[ni] * __sinf(thv[ni] + 0.1f * h);
          unsigned short v = f2bf(fmaxf(q, 0.f));
          int ad = SB + row16 * 128 +
                   (((ni * 16 + lr) * 2) ^ ((row16 & 7) << 4));
          *(unsigned short*)&lds[ad] = v;
        }
      }
      s16x8 w0 = *(const s16x8*)&lds[SB + rd * 128 + (bo ^ ((rd & 7) << 4))];
      s16x8 w1 = *(const s16x8*)&lds[SB + (rd + 8) * 128 +
                                     (bo ^ ((rd & 7) << 4))];
      unsigned short* dst = Cout + growB + (size_t)(mi * 16 + rd) * N +
                            colR + wc * 64 + (lane & 7) * 8;
      *(s16x8*)dst = w0;
      *(s16x8*)(dst + (size_t)8 * N) = w1;   // rows rd and rd+8
    }

    if (rep + 1 < REPS) {
      asm volatile("s_waitcnt vmcnt(16)" ::: "memory");
      BAR();
    }
  }
#undef WIN
#undef QUAD
#undef LOAD_A
#undef LOAD_B
#undef STAGE_AU
#undef STAGE_BU
#undef BAR
#undef LG0
}

// ================= GEMM2: out = actb @ w2t^T + b2 (fp32) =================
// R15 verbatim (2-barrier window schedule; ~59-62 us, within ~2% of its
// LDS-pipe floor for this fragment geometry).

__global__ __launch_bounds__(512, 1) void gemm2k(
    const unsigned short* __restrict__ A,    // actb [8192][4096]
    const unsigned short* __restrict__ Bt,   // w2t  [1024][4096]
    const float* __restrict__ bias,
    float* __restrict__ Cout) {              // out [8192][1024]
  constexpr int K = 4096, N = 1024, NT = 64;
  constexpr int WROWS = 64, M_REP = 4, MH = 2;
  constexpr int ABYTES = 16384, AH = 8192, AL = 1;
  constexpr int BUFSZ = 49152;
  constexpr int nTilesN = 4;

  __shared__ __align__(16) char lds[2 * BUFSZ + 32768];

  int nwg = gridDim.x;
  int wg = blockIdx.x;
  int sw = (wg & 7) * (nwg >> 3) + (wg >> 3);
  int rowBase = (sw / nTilesN) * 128;
  int colBase = (sw % nTilesN) * 256;

  const int t = threadIdx.x;
  const int lane = t & 63;
  const int wid = t >> 6;
  const int wr = wid >> 2, wc = wid & 3;
  const int lr = lane & 15;
  const int lg = lane >> 4;
  const int r7 = lane & 7;

  const int srow = t >> 3;
  const int scolB = ((t & 7) * 16) ^ ((srow & 7) << 4);
  const unsigned short* aSrcB = A  + (size_t)(rowBase + srow) * K + (scolB >> 1);
  const unsigned short* bSrcB = Bt + (size_t)(colBase + srow) * K + (scolB >> 1);

  const int aRd = (wr * WROWS + lr) * 128 + ((lg ^ r7) << 4);
  const int bRd = ABYTES + (wc * 64 + lr) * 128 + ((lg ^ r7) << 4);

  f32x4 acc[M_REP][4] = {};
  bf16x8 a[MH][2], b[4][2];

#define STAGE_AU(S, U, P)                                                   \
  async16(aSrcB + ((size_t)((U) * 64) * K + (size_t)(S) * 64),              \
          &lds[(P) * BUFSZ + (U) * AH + t * 16])
#define STAGE_BU(S, U, P) do {                                              \
    _Pragma("unroll") for (int j = 0; j < 2; ++j)                           \
      async16(bSrcB + ((size_t)((U) * 128 + j * 64) * K + (size_t)(S) * 64),\
              &lds[(P) * BUFSZ + ABYTES + (U) * 16384 + j * 8192 + t * 16]);\
  } while (0)
#define LOAD_A(MHh, P)                                                      \
  _Pragma("unroll") for (int mi = 0; mi < MH; ++mi)                         \
  _Pragma("unroll") for (int ks = 0; ks < 2; ++ks)                          \
    a[mi][ks] = __builtin_bit_cast(bf16x8, *(const s16x8*)&lds[             \
        (P) * BUFSZ + ((aRd + ((MHh) * MH + mi) * 2048) ^ (ks << 6))])
#define LOAD_B(NHh, P)                                                      \
  _Pragma("unroll") for (int nn = 0; nn < 2; ++nn)                          \
  _Pragma("unroll") for (int ks = 0; ks < 2; ++ks)                          \
    b[(NHh) * 2 + nn][ks] = __builtin_bit_cast(bf16x8, *(const s16x8*)&lds[ \
        (P) * BUFSZ + ((bRd + ((NHh) * 2 + nn) * 2048) ^ (ks << 6))])
#define QUAD(MHh, NHh)                                                      \
  __builtin_amdgcn_s_setprio(1);                                            \
  _Pragma("unroll") for (int mi = 0; mi < MH; ++mi)                         \
  _Pragma("unroll") for (int nn = 0; nn < 2; ++nn)                          \
  _Pragma("unroll") for (int ks = 0; ks < 2; ++ks)                          \
    acc[(MHh) * MH + mi][(NHh) * 2 + nn] =                                  \
        __builtin_amdgcn_mfma_f32_16x16x32_bf16(                            \
            a[mi][ks], b[(NHh) * 2 + nn][ks],                               \
            acc[(MHh) * MH + mi][(NHh) * 2 + nn], 0, 0, 0);                 \
  __builtin_amdgcn_s_setprio(0)
#define BAR() __builtin_amdgcn_s_barrier()
#define LG0() asm volatile("s_waitcnt lgkmcnt(0)" ::: "memory")
#define WIN(T, P) do {                                                      \
    /* half 1 */                                                            \
    LOAD_A(0, P); LOAD_B(0, P);                                             \
    if ((T) + 1 < NT) {                                                     \
      STAGE_AU((T) + 1, 0, (P) ^ 1);                                        \
      STAGE_AU((T) + 1, 1, (P) ^ 1);                                        \
    }                                                                       \
    QUAD(0, 0);                                                             \
    LOAD_B(1, P);                                                           \
    QUAD(0, 1);                                                             \
    LG0(); BAR();                                                           \
    /* half 2 */                                                            \
    LOAD_A(1, P);                                                           \
    if ((T) + 2 < NT) {                                                     \
      STAGE_BU((T) + 2, 0, P);                                              \
      STAGE_BU((T) + 2, 1, P);                                              \
    }                                                                       \
    QUAD(1, 0);                                                             \
    QUAD(1, 1);                                                             \
    LG0();                                                                  \
    if ((T) < NT - 2) {                                                     \
      asm volatile("s_waitcnt vmcnt(4)" ::: "memory");                      \
    } else if ((T) == NT - 2) {                                             \
      asm volatile("s_waitcnt vmcnt(0)" ::: "memory");                      \
    }                                                                       \
    BAR();                                                                  \
  } while (0)

  STAGE_AU(0, 0, 0); STAGE_AU(0, 1, 0);
  STAGE_BU(0, 0, 0); STAGE_BU(0, 1, 0);
  STAGE_BU(1, 0, 1); STAGE_BU(1, 1, 1);
  asm volatile("s_waitcnt vmcnt(4)" ::: "memory");
  BAR();

  for (int T = 0; T < NT; T += 2) {
    WIN(T, 0);
    WIN(T + 1, 1);
  }
#undef WIN
#undef QUAD
#undef LOAD_A
#undef LOAD_B
#undef STAGE_AU
#undef STAGE_BU
#undef BAR

  // ---- full-line fp32 epilogue via per-wave 4KB scratch ----
  const int ocol0 = colBase + wc * 64 + lr;
  float bvv[4];
#pragma unroll
  for (int ni = 0; ni < 4; ++ni) bvv[ni] = bias[ocol0 + ni * 16];
  const int SB = 2 * BUFSZ + wid * 4096;
  const int orowB = rowBase + wr * WROWS;
  const int rd = lane >> 3;                  // 0..7
  const int bo = (lane & 7) * 16;            // 0..112
#pragma unroll
  for (int mi = 0; mi < M_REP; ++mi) {
#pragma unroll
    for (int ni = 0; ni < 4; ++ni) {
#pragma unroll
      for (int r = 0; r < 4; ++r) {
        int row16 = lg * 4 + r;
        int ad = SB + row16 * 256 +
                 (((ni * 16 + lr) * 4) ^ ((row16 & 7) << 4));
        *(float*)&lds[ad] = acc[mi][ni][r] + bvv[ni];
      }
    }
    asm volatile("s_waitcnt lgkmcnt(0)" ::: "memory");
    f32x4 v00 = *(const f32x4*)&lds[SB + rd * 256 + (bo ^ ((rd & 7) << 4))];
    f32x4 v01 = *(const f32x4*)&lds[SB + rd * 256 +
                                    ((bo + 128) ^ ((rd & 7) << 4))];
    f32x4 v10 = *(const f32x4*)&lds[SB + (rd + 8) * 256 +
                                    (bo ^ ((rd & 7) << 4))];
    f32x4 v11 = *(const f32x4*)&lds[SB + (rd + 8) * 256 +
                                    ((bo + 128) ^ ((rd & 7) << 4))];
    float* dst0 = Cout + (size_t)(orowB + mi * 16 + rd) * N +
                  colBase + wc * 64 + (lane & 7) * 4;
    *(f32x4*)dst0 = v00;
    *(f32x4*)(dst0 + 32) = v01;
    float* dst1 = dst0 + (size_t)8 * N;
    *(f32x4*)dst1 = v10;
    *(f32x4*)(dst1 + 32) = v11;
    asm volatile("s_waitcnt lgkmcnt(0)" ::: "memory");
  }
#undef LG0
}

// ---------------- launch ----------------

extern "C" void kernel_launch(void* const* d_in, const int* in_sizes, int n_in,
                              void* d_out, int out_size, void* d_ws,
                              size_t ws_size, hipStream_t stream) {
  const float* x     = (const float*)d_in[0];
  const float* W1    = (const float*)d_in[1];
  const float* b1    = (const float*)d_in[2];
  const float* theta = (const float*)d_in[3];
  const float* qwr   = (const float*)d_in[4];
  const float* qwi   = (const float*)d_in[5];
  const float* W2    = (const float*)d_in[6];
  const float* b2    = (const float*)d_in[7];
  float* out = (float*)d_out;

  const int DF = 4096;
  size_t need = ((size_t)96 << 20) + DF * sizeof(float);
  if (ws_size < need) return;

  char* ws = (char*)d_ws;
  unsigned short* xb   = (unsigned short*)ws;                          // 16 MiB
  unsigned short* w1t  = (unsigned short*)(ws + ((size_t)16 << 20));   //  8 MiB
  unsigned short* w2t  = (unsigned short*)(ws + ((size_t)24 << 20));   //  8 MiB
  unsigned short* actb = (unsigned short*)(ws + ((size_t)32 << 20));   // 64 MiB
  float* c1 = (float*)(ws + ((size_t)96 << 20));

  prep<<<9232, 256, 0, stream>>>(x, W1, W2, theta, qwr, qwi,
                                 xb, w1t, w2t, c1);
  gemm1k<<<256, 512, 0, stream>>>(xb, w1t, b1, theta, c1, actb);
  gemm2k<<<256, 512, 0, stream>>>(actb, w2t, b2, out);
}